// Round 1
// baseline (632.668 us; speedup 1.0000x reference)
//
#include <hip/hip_runtime.h>
#include <hip/hip_bf16.h>
#include <cstddef>

// Problem constants (N=4096 fixed by setup_inputs).
// Levels l=0..4: s = 8<<l, T = 2s+1, offsets o[t] = t - s, targets xjk = (t-s)/s.
//   l=0: base (j0=3), F = img gather (no threshold)
//   l=1..4: detail j=3..6, D = threshold(f - u)
#define NN 4096
#define KP 512          // padded K (501 real cols)
#define KTOT 501

__device__ __forceinline__ float phi_eval(float x) {
    const float PI_F = 3.14159265358979323846f;
    float t = PI_F * x;
    if (t == 0.0f) return 1.0f;
    const float MMf = 3.2f * 3.2f;
    return sinf(t) * expf(-x * x / (2.0f * MMf)) / t;
}

__device__ __forceinline__ void col_to_level(int col, int& l, int& off) {
    if      (col < 17)  { l = 0; off = 0;   }
    else if (col < 50)  { l = 1; off = 17;  }
    else if (col < 115) { l = 2; off = 50;  }
    else if (col < 244) { l = 3; off = 115; }
    else                { l = 4; off = 244; }
}

// Fill PhiC[n][col], PhiR[n][col] for col<501; zero pad cols 501..511.
__global__ void phi_kernel(const float* __restrict__ xc, const float* __restrict__ xr,
                           float* __restrict__ PhiC, float* __restrict__ PhiR) {
    int col = blockIdx.x * blockDim.x + threadIdx.x;   // 0..511
    int n   = blockIdx.y;
    float pc = 0.0f, pr = 0.0f;
    if (col < KTOT) {
        int l, off; col_to_level(col, l, off);
        int s = 8 << l;
        float fo = (float)(col - off - s);
        float fs = (float)s;
        pc = phi_eval(fs * xc[n] - fo);
        pr = phi_eval(fs * xr[n] - fo);
    }
    PhiC[(size_t)n * KP + col] = pc;
    PhiR[(size_t)n * KP + col] = pr;
}

// For each global column (level-local target), find argmin_n |x[n]-target| with
// first-occurrence tie-break (matches jnp.argmin). grid=(501,2), block=256.
__global__ void nearest_kernel(const float* __restrict__ xc, const float* __restrict__ xr,
                               int* __restrict__ idxAll) {
    int col  = blockIdx.x;
    int side = blockIdx.y;               // 0 = xc (rows), 1 = xr (cols)
    const float* x = side ? xr : xc;
    int l, off; col_to_level(col, l, off);
    int s = 8 << l;
    float target = (float)(col - off - s) / (float)s;

    __shared__ float sv[256];
    __shared__ int   si[256];
    int tid = threadIdx.x;
    float best = 1e30f; int bidx = 0;
    for (int n = tid; n < NN; n += 256) {
        float d = fabsf(x[n] - target);
        if (d < best) { best = d; bidx = n; }   // strict < keeps lowest n within thread
    }
    sv[tid] = best; si[tid] = bidx;
    __syncthreads();
    for (int w = 128; w > 0; w >>= 1) {
        if (tid < w) {
            float ov = sv[tid + w]; int oi = si[tid + w];
            if (ov < sv[tid] || (ov == sv[tid] && oi < si[tid])) { sv[tid] = ov; si[tid] = oi; }
        }
        __syncthreads();
    }
    if (tid == 0) idxAll[side * KTOT + col] = si[0];
}

// Zero U pad columns 501..511 (ws is poisoned 0xAA each call).
__global__ void zero_padU(float* __restrict__ U) {
    int idx = blockIdx.x * 256 + threadIdx.x;
    if (idx >= NN * (KP - KTOT)) return;
    int n = idx / (KP - KTOT);
    int c = KTOT + idx % (KP - KTOT);
    U[(size_t)n * KP + c] = 0.0f;
}

// C_l[p][q]: level 0 -> img gather; levels >=1 -> threshold(f - u),
// u = sum_{k<off} U[ic[p],k] * PhiR[ir[q],k]  (approx at sampled points).
__global__ void build_C_kernel(const float* __restrict__ img, const int* __restrict__ idxAll,
                               const float* __restrict__ U, const float* __restrict__ PhiR,
                               float* __restrict__ C, int T, int off, int coff) {
    int q = blockIdx.x * 16 + threadIdx.x;
    int p = blockIdx.y * 16 + threadIdx.y;
    if (p >= T || q >= T) return;
    int ip = idxAll[off + p];
    int iq = idxAll[KTOT + off + q];
    float f = img[(size_t)ip * NN + iq];
    float val;
    if (off == 0) {
        val = f;
    } else {
        const float* Ur = U    + (size_t)ip * KP;
        const float* Pr = PhiR + (size_t)iq * KP;
        float u = 0.0f;
        for (int k = 0; k < off; ++k) u += Ur[k] * Pr[k];
        float d = f - u;
        val = (fabsf(d) > 0.01f) ? d : 0.0f;
    }
    C[coff + p * T + q] = val;
}

// U[n, off+t] = sum_q PhiC[n, off+q] * C_l[q][t].  block (64,4), grid (ceil(T/64),1024)
__global__ void update_U_kernel(const float* __restrict__ PhiC, const float* __restrict__ C,
                                float* __restrict__ U, int T, int off, int coff) {
    int t = blockIdx.x * 64 + threadIdx.x;
    int n = blockIdx.y * 4 + threadIdx.y;
    if (t >= T) return;
    const float* Pc = PhiC + (size_t)n * KP + off;
    const float* Cl = C + coff;
    float acc = 0.0f;
    for (int q = 0; q < T; ++q) acc += Pc[q] * Cl[q * T + t];
    U[(size_t)n * KP + off + t] = acc;
}

// out(4096x4096) = U(4096x512) * PhiR(4096x512)^T.  fp32 VALU GEMM.
// Block: 256 threads, 128x128 tile, TK=16, each thread 8x8 spread as 2x2 of 4x4.
__global__ __launch_bounds__(256) void gemm_kernel(const float* __restrict__ U,
                                                   const float* __restrict__ P,
                                                   float* __restrict__ out) {
    __shared__ float As[16][128];   // k-major
    __shared__ float Bs[16][128];
    int tid = threadIdx.x;
    int tx = tid & 15;              // col group
    int ty = tid >> 4;              // row group
    int row0 = blockIdx.y * 128;
    int col0 = blockIdx.x * 128;

    float acc[2][2][4][4];
    #pragma unroll
    for (int a = 0; a < 2; a++)
        #pragma unroll
        for (int b = 0; b < 2; b++)
            #pragma unroll
            for (int i = 0; i < 4; i++)
                #pragma unroll
                for (int j = 0; j < 4; j++) acc[a][b][i][j] = 0.0f;

    for (int k0 = 0; k0 < KP; k0 += 16) {
        // stage: 128 rows x 16 k per tile = 512 float4; 2 per thread per matrix
        #pragma unroll
        for (int rep = 0; rep < 2; rep++) {
            int id = rep * 256 + tid;
            int r = id >> 2;
            int q = id & 3;
            const float4 a4 = *(const float4*)(U + (size_t)(row0 + r) * KP + k0 + q * 4);
            const float4 b4 = *(const float4*)(P + (size_t)(col0 + r) * KP + k0 + q * 4);
            As[q * 4 + 0][r] = a4.x; As[q * 4 + 1][r] = a4.y;
            As[q * 4 + 2][r] = a4.z; As[q * 4 + 3][r] = a4.w;
            Bs[q * 4 + 0][r] = b4.x; Bs[q * 4 + 1][r] = b4.y;
            Bs[q * 4 + 2][r] = b4.z; Bs[q * 4 + 3][r] = b4.w;
        }
        __syncthreads();
        #pragma unroll
        for (int k = 0; k < 16; k++) {
            float4 a0 = *(const float4*)&As[k][ty * 4];
            float4 a1 = *(const float4*)&As[k][64 + ty * 4];
            float4 b0 = *(const float4*)&Bs[k][tx * 4];
            float4 b1 = *(const float4*)&Bs[k][64 + tx * 4];
            float av[2][4] = {{a0.x, a0.y, a0.z, a0.w}, {a1.x, a1.y, a1.z, a1.w}};
            float bv[2][4] = {{b0.x, b0.y, b0.z, b0.w}, {b1.x, b1.y, b1.z, b1.w}};
            #pragma unroll
            for (int a = 0; a < 2; a++)
                #pragma unroll
                for (int b = 0; b < 2; b++)
                    #pragma unroll
                    for (int i = 0; i < 4; i++)
                        #pragma unroll
                        for (int j = 0; j < 4; j++)
                            acc[a][b][i][j] += av[a][i] * bv[b][j];
        }
        __syncthreads();
    }

    #pragma unroll
    for (int a = 0; a < 2; a++)
        #pragma unroll
        for (int i = 0; i < 4; i++) {
            int row = row0 + a * 64 + ty * 4 + i;
            float4 o0 = make_float4(acc[a][0][i][0], acc[a][0][i][1], acc[a][0][i][2], acc[a][0][i][3]);
            float4 o1 = make_float4(acc[a][1][i][0], acc[a][1][i][1], acc[a][1][i][2], acc[a][1][i][3]);
            *(float4*)(out + (size_t)row * NN + col0 + tx * 4)      = o0;
            *(float4*)(out + (size_t)row * NN + col0 + 64 + tx * 4) = o1;
        }
}

extern "C" void kernel_launch(void* const* d_in, const int* in_sizes, int n_in,
                              void* d_out, int out_size, void* d_ws, size_t ws_size,
                              hipStream_t stream) {
    const float* img = (const float*)d_in[0];
    const float* xc  = (const float*)d_in[1];
    const float* xr  = (const float*)d_in[2];
    float* out = (float*)d_out;

    // workspace layout (floats): PhiC | PhiR | U | C(88293) | idx(1002 ints)
    float* PhiC = (float*)d_ws;
    float* PhiR = PhiC + (size_t)NN * KP;
    float* U    = PhiR + (size_t)NN * KP;
    float* C    = U    + (size_t)NN * KP;
    int*   idxAll = (int*)(C + 88293);

    phi_kernel<<<dim3(2, NN), 256, 0, stream>>>(xc, xr, PhiC, PhiR);
    nearest_kernel<<<dim3(KTOT, 2), 256, 0, stream>>>(xc, xr, idxAll);
    zero_padU<<<dim3((NN * (KP - KTOT) + 255) / 256), 256, 0, stream>>>(U);

    const int Ts[5]    = {17, 33, 65, 129, 257};
    const int offs[5]  = {0, 17, 50, 115, 244};
    const int coffs[5] = {0, 289, 1378, 5603, 22244};
    for (int l = 0; l < 5; l++) {
        dim3 bgrid((Ts[l] + 15) / 16, (Ts[l] + 15) / 16);
        build_C_kernel<<<bgrid, dim3(16, 16), 0, stream>>>(img, idxAll, U, PhiR, C,
                                                           Ts[l], offs[l], coffs[l]);
        dim3 ugrid((Ts[l] + 63) / 64, NN / 4);
        update_U_kernel<<<ugrid, dim3(64, 4), 0, stream>>>(PhiC, C, U,
                                                           Ts[l], offs[l], coffs[l]);
    }

    gemm_kernel<<<dim3(NN / 128, NN / 128), 256, 0, stream>>>(U, PhiR, out);
}

// Round 2
// 412.833 us; speedup vs baseline: 1.5325x; 1.5325x over previous
//
#include <hip/hip_runtime.h>
#include <hip/hip_bf16.h>
#include <cstddef>

#define NN 4096
#define KP 512          // padded K (501 real cols)
#define KTOT 501

typedef __attribute__((ext_vector_type(8))) short short8;
typedef __attribute__((ext_vector_type(4))) float f32x4;

#define GLB(p) ((const __attribute__((address_space(1))) void*)(p))
#define LDS(p) ((__attribute__((address_space(3))) void*)(p))

// phi(x) = sin(pi x)/(pi x) * exp(-x^2/(2*3.2^2)), phi(0)=1.
// sin(pi x) via parity reduction: r = x - rint(x), sin(pi x) = (-1)^rint * sin(pi r).
__device__ __forceinline__ float phi_eval(float x) {
    if (x == 0.0f) return 1.0f;
    const float PI_F = 3.14159265358979323846f;
    float rn = rintf(x);
    float r  = x - rn;
    float s  = __sinf(PI_F * r);
    if (((int)rn) & 1) s = -s;
    float e  = __expf(-x * x * (1.0f / 20.48f));   // 2*MM = 20.48
    return __fdividef(s * e, PI_F * x);
}

__device__ __forceinline__ void col_to_level(int col, int& l, int& off) {
    if      (col < 17)  { l = 0; off = 0;   }
    else if (col < 50)  { l = 1; off = 17;  }
    else if (col < 115) { l = 2; off = 50;  }
    else if (col < 244) { l = 3; off = 115; }
    else                { l = 4; off = 244; }
}

__global__ void phi_kernel(const float* __restrict__ xc, const float* __restrict__ xr,
                           float* __restrict__ PhiC, float* __restrict__ PhiR) {
    int col = blockIdx.x * blockDim.x + threadIdx.x;   // 0..511
    int n   = blockIdx.y;
    float pc = 0.0f, pr = 0.0f;
    if (col < KTOT) {
        int l, off; col_to_level(col, l, off);
        int s = 8 << l;
        float fo = (float)(col - off - s);
        float fs = (float)s;
        pc = phi_eval(fs * xc[n] - fo);
        pr = phi_eval(fs * xr[n] - fo);
    }
    PhiC[(size_t)n * KP + col] = pc;
    PhiR[(size_t)n * KP + col] = pr;
}

__global__ void nearest_kernel(const float* __restrict__ xc, const float* __restrict__ xr,
                               int* __restrict__ idxAll) {
    int col  = blockIdx.x;
    int side = blockIdx.y;
    const float* x = side ? xr : xc;
    int l, off; col_to_level(col, l, off);
    int s = 8 << l;
    float target = (float)(col - off - s) / (float)s;

    __shared__ float sv[256];
    __shared__ int   si[256];
    int tid = threadIdx.x;
    float best = 1e30f; int bidx = 0;
    for (int n = tid; n < NN; n += 256) {
        float d = fabsf(x[n] - target);
        if (d < best) { best = d; bidx = n; }
    }
    sv[tid] = best; si[tid] = bidx;
    __syncthreads();
    for (int w = 128; w > 0; w >>= 1) {
        if (tid < w) {
            float ov = sv[tid + w]; int oi = si[tid + w];
            if (ov < sv[tid] || (ov == sv[tid] && oi < si[tid])) { sv[tid] = ov; si[tid] = oi; }
        }
        __syncthreads();
    }
    if (tid == 0) idxAll[side * KTOT + col] = si[0];
}

__global__ void zero_padU(float* __restrict__ U) {
    int idx = blockIdx.x * 256 + threadIdx.x;
    if (idx >= NN * (KP - KTOT)) return;
    int n = idx / (KP - KTOT);
    int c = KTOT + idx % (KP - KTOT);
    U[(size_t)n * KP + c] = 0.0f;
}

__global__ void build_C_kernel(const float* __restrict__ img, const int* __restrict__ idxAll,
                               const float* __restrict__ U, const float* __restrict__ PhiR,
                               float* __restrict__ C, int T, int off, int coff) {
    int q = blockIdx.x * 16 + threadIdx.x;
    int p = blockIdx.y * 16 + threadIdx.y;
    if (p >= T || q >= T) return;
    int ip = idxAll[off + p];
    int iq = idxAll[KTOT + off + q];
    float f = img[(size_t)ip * NN + iq];
    float val;
    if (off == 0) {
        val = f;
    } else {
        const float* Ur = U    + (size_t)ip * KP;
        const float* Pr = PhiR + (size_t)iq * KP;
        float u = 0.0f;
        for (int k = 0; k < off; ++k) u += Ur[k] * Pr[k];
        float d = f - u;
        val = (fabsf(d) > 0.01f) ? d : 0.0f;
    }
    C[coff + p * T + q] = val;
}

// U[n, off+t] = sum_q PhiC[n, off+q] * C_l[q][t].  4 rows per thread.
// block (64,4), grid (ceil(T/64), 256)
__global__ void update_U_kernel(const float* __restrict__ PhiC, const float* __restrict__ C,
                                float* __restrict__ U, int T, int off, int coff) {
    int t  = blockIdx.x * 64 + threadIdx.x;
    int n0 = (blockIdx.y * 4 + threadIdx.y) * 4;
    if (t >= T) return;
    const float* Cl = C + coff;
    const float* P0 = PhiC + (size_t)n0 * KP + off;
    float a0 = 0.f, a1 = 0.f, a2 = 0.f, a3 = 0.f;
    for (int q = 0; q < T; ++q) {
        float c = Cl[q * T + t];
        a0 += P0[q]          * c;
        a1 += P0[KP + q]     * c;
        a2 += P0[2 * KP + q] * c;
        a3 += P0[3 * KP + q] * c;
    }
    U[(size_t)n0       * KP + off + t] = a0;
    U[(size_t)(n0 + 1) * KP + off + t] = a1;
    U[(size_t)(n0 + 2) * KP + off + t] = a2;
    U[(size_t)(n0 + 3) * KP + off + t] = a3;
}

// fp32 -> bf16 hi + bf16 lo(residual). 4 elements/thread.
__global__ void split_kernel(const float* __restrict__ src, __hip_bfloat16* __restrict__ hi,
                             __hip_bfloat16* __restrict__ lo) {
    int i = (blockIdx.x * 256 + threadIdx.x) * 4;
    float4 v = *(const float4*)(src + i);
    __hip_bfloat16 h[4], l[4];
    float vv[4] = {v.x, v.y, v.z, v.w};
    #pragma unroll
    for (int j = 0; j < 4; ++j) {
        h[j] = __float2bfloat16(vv[j]);
        l[j] = __float2bfloat16(vv[j] - __bfloat162float(h[j]));
    }
    *(ushort4*)(hi + i) = *(const ushort4*)h;
    *(ushort4*)(lo + i) = *(const ushort4*)l;
}

// out(4096x4096) = (Ahi+Alo)(4096x512) * (Bhi+Blo)^T, dropping lo*lo.
// 128x128 tile, 256 threads (4 waves, each 64x64 as 4x4 of 16x16x32 MFMA).
__global__ __launch_bounds__(256) void gemm_mfma(const short* __restrict__ Ahi,
                                                 const short* __restrict__ Alo,
                                                 const short* __restrict__ Bhi,
                                                 const short* __restrict__ Blo,
                                                 float* __restrict__ out) {
    __shared__ short As_h[128][32];
    __shared__ short As_l[128][32];
    __shared__ short Bs_h[128][32];
    __shared__ short Bs_l[128][32];

    const int tid  = threadIdx.x;
    const int lane = tid & 63;
    const int wave = tid >> 6;
    const int wr   = wave >> 1;
    const int wc   = wave & 1;
    const int row0 = blockIdx.y * 128;
    const int col0 = blockIdx.x * 128;

    f32x4 acc[4][4];
    #pragma unroll
    for (int i = 0; i < 4; ++i)
        #pragma unroll
        for (int j = 0; j < 4; ++j)
            acc[i][j] = (f32x4){0.f, 0.f, 0.f, 0.f};

    const int srow = lane >> 2;          // 0..15 within 16-row segment
    const int scol = (lane & 3) * 8;     // bf16 element offset (16B granules)

    for (int kc = 0; kc < 16; ++kc) {
        const int k0 = kc * 32;
        #pragma unroll
        for (int s = 0; s < 2; ++s) {
            const int rseg = wave * 32 + s * 16;
            const int r    = rseg + srow;
            const size_t ga = (size_t)(row0 + r) * KP + k0 + scol;
            const size_t gb = (size_t)(col0 + r) * KP + k0 + scol;
            __builtin_amdgcn_global_load_lds(GLB(Ahi + ga), LDS(&As_h[rseg][0]), 16, 0, 0);
            __builtin_amdgcn_global_load_lds(GLB(Alo + ga), LDS(&As_l[rseg][0]), 16, 0, 0);
            __builtin_amdgcn_global_load_lds(GLB(Bhi + gb), LDS(&Bs_h[rseg][0]), 16, 0, 0);
            __builtin_amdgcn_global_load_lds(GLB(Blo + gb), LDS(&Bs_l[rseg][0]), 16, 0, 0);
        }
        __syncthreads();

        const int kb = (lane >> 4) * 8;
        short8 ah[4], al[4], bh[4], bl[4];
        #pragma unroll
        for (int mb = 0; mb < 4; ++mb) {
            const int rr = wr * 64 + mb * 16 + (lane & 15);
            ah[mb] = *(const short8*)&As_h[rr][kb];
            al[mb] = *(const short8*)&As_l[rr][kb];
        }
        #pragma unroll
        for (int nb = 0; nb < 4; ++nb) {
            const int cc = wc * 64 + nb * 16 + (lane & 15);
            bh[nb] = *(const short8*)&Bs_h[cc][kb];
            bl[nb] = *(const short8*)&Bs_l[cc][kb];
        }
        #pragma unroll
        for (int mb = 0; mb < 4; ++mb)
            #pragma unroll
            for (int nb = 0; nb < 4; ++nb) {
                acc[mb][nb] = __builtin_amdgcn_mfma_f32_16x16x32_bf16(ah[mb], bh[nb], acc[mb][nb], 0, 0, 0);
                acc[mb][nb] = __builtin_amdgcn_mfma_f32_16x16x32_bf16(ah[mb], bl[nb], acc[mb][nb], 0, 0, 0);
                acc[mb][nb] = __builtin_amdgcn_mfma_f32_16x16x32_bf16(al[mb], bh[nb], acc[mb][nb], 0, 0, 0);
            }
        __syncthreads();
    }

    // C/D layout: col = lane&15, row = (lane>>4)*4 + reg  [m89-verified]
    const int orow = (lane >> 4) * 4;
    const int ocol = lane & 15;
    #pragma unroll
    for (int mb = 0; mb < 4; ++mb)
        #pragma unroll
        for (int nb = 0; nb < 4; ++nb) {
            const int col = col0 + wc * 64 + nb * 16 + ocol;
            #pragma unroll
            for (int reg = 0; reg < 4; ++reg) {
                const int row = row0 + wr * 64 + mb * 16 + orow + reg;
                out[(size_t)row * NN + col] = acc[mb][nb][reg];
            }
        }
}

extern "C" void kernel_launch(void* const* d_in, const int* in_sizes, int n_in,
                              void* d_out, int out_size, void* d_ws, size_t ws_size,
                              hipStream_t stream) {
    const float* img = (const float*)d_in[0];
    const float* xc  = (const float*)d_in[1];
    const float* xr  = (const float*)d_in[2];
    float* out = (float*)d_out;

    // ws layout (floats): PhiC(8MB) | PhiR(8MB) | U(8MB) | C(353KB) | idx
    float* PhiC = (float*)d_ws;
    float* PhiR = PhiC + (size_t)NN * KP;
    float* U    = PhiR + (size_t)NN * KP;
    float* C    = U    + (size_t)NN * KP;
    int*   idxAll = (int*)(C + 88293);
    // bf16 split arrays overlay dead fp32 regions:
    //   Ahi/Alo over PhiC (dead after levels), Bhi/Blo over U (dead after split #1)
    short* Ahi = (short*)PhiC;
    short* Alo = Ahi + (size_t)NN * KP;
    short* Bhi = (short*)U;
    short* Blo = Bhi + (size_t)NN * KP;

    phi_kernel<<<dim3(2, NN), 256, 0, stream>>>(xc, xr, PhiC, PhiR);
    nearest_kernel<<<dim3(KTOT, 2), 256, 0, stream>>>(xc, xr, idxAll);
    zero_padU<<<dim3((NN * (KP - KTOT) + 255) / 256), 256, 0, stream>>>(U);

    const int Ts[5]    = {17, 33, 65, 129, 257};
    const int offs[5]  = {0, 17, 50, 115, 244};
    const int coffs[5] = {0, 289, 1378, 5603, 22244};
    for (int l = 0; l < 5; l++) {
        dim3 bgrid((Ts[l] + 15) / 16, (Ts[l] + 15) / 16);
        build_C_kernel<<<bgrid, dim3(16, 16), 0, stream>>>(img, idxAll, U, PhiR, C,
                                                           Ts[l], offs[l], coffs[l]);
        dim3 ugrid((Ts[l] + 63) / 64, NN / 16);
        update_U_kernel<<<ugrid, dim3(64, 4), 0, stream>>>(PhiC, C, U,
                                                           Ts[l], offs[l], coffs[l]);
    }

    // split U -> Ahi/Alo (overwrites PhiC), then PhiR -> Bhi/Blo (overwrites U)
    split_kernel<<<dim3(NN * KP / 1024), 256, 0, stream>>>(U, (__hip_bfloat16*)Ahi,
                                                           (__hip_bfloat16*)Alo);
    split_kernel<<<dim3(NN * KP / 1024), 256, 0, stream>>>(PhiR, (__hip_bfloat16*)Bhi,
                                                           (__hip_bfloat16*)Blo);

    gemm_mfma<<<dim3(NN / 128, NN / 128), 256, 0, stream>>>(Ahi, Alo, Bhi, Blo, out);
}

// Round 3
// 340.367 us; speedup vs baseline: 1.8588x; 1.2129x over previous
//
#include <hip/hip_runtime.h>
#include <hip/hip_bf16.h>
#include <cstddef>

#define NN 4096
#define KP 512          // padded K (501 real cols)
#define KTOT 501

typedef __attribute__((ext_vector_type(8))) short short8;
typedef __attribute__((ext_vector_type(4))) float f32x4;

#define GLB(p) ((const __attribute__((address_space(1))) void*)(p))
#define LDS(p) ((__attribute__((address_space(3))) void*)(p))

// phi(x) = sin(pi x)/(pi x) * exp(-x^2/(2*3.2^2)), phi(0)=1.
__device__ __forceinline__ float phi_eval(float x) {
    if (x == 0.0f) return 1.0f;
    const float PI_F = 3.14159265358979323846f;
    float rn = rintf(x);
    float r  = x - rn;
    float s  = __sinf(PI_F * r);
    if (((int)rn) & 1) s = -s;
    float e  = __expf(-x * x * (1.0f / 20.48f));
    return __fdividef(s * e, PI_F * x);
}

__device__ __forceinline__ void col_to_level(int col, int& l, int& off) {
    if      (col < 17)  { l = 0; off = 0;   }
    else if (col < 50)  { l = 1; off = 17;  }
    else if (col < 115) { l = 2; off = 50;  }
    else if (col < 244) { l = 3; off = 115; }
    else                { l = 4; off = 244; }
}

__global__ void phi_kernel(const float* __restrict__ xc, const float* __restrict__ xr,
                           float* __restrict__ PhiC, float* __restrict__ PhiR) {
    int col = blockIdx.x * blockDim.x + threadIdx.x;   // 0..511
    int n   = blockIdx.y;
    float pc = 0.0f, pr = 0.0f;
    if (col < KTOT) {
        int l, off; col_to_level(col, l, off);
        int s = 8 << l;
        float fo = (float)(col - off - s);
        float fs = (float)s;
        pc = phi_eval(fs * xc[n] - fo);
        pr = phi_eval(fs * xr[n] - fo);
    }
    PhiC[(size_t)n * KP + col] = pc;
    PhiR[(size_t)n * KP + col] = pr;
}

__global__ void nearest_kernel(const float* __restrict__ xc, const float* __restrict__ xr,
                               int* __restrict__ idxAll) {
    int col  = blockIdx.x;
    int side = blockIdx.y;
    const float* x = side ? xr : xc;
    int l, off; col_to_level(col, l, off);
    int s = 8 << l;
    float target = (float)(col - off - s) / (float)s;

    __shared__ float sv[256];
    __shared__ int   si[256];
    int tid = threadIdx.x;
    float best = 1e30f; int bidx = 0;
    for (int n = tid; n < NN; n += 256) {
        float d = fabsf(x[n] - target);
        if (d < best) { best = d; bidx = n; }
    }
    sv[tid] = best; si[tid] = bidx;
    __syncthreads();
    for (int w = 128; w > 0; w >>= 1) {
        if (tid < w) {
            float ov = sv[tid + w]; int oi = si[tid + w];
            if (ov < sv[tid] || (ov == sv[tid] && oi < si[tid])) { sv[tid] = ov; si[tid] = oi; }
        }
        __syncthreads();
    }
    if (tid == 0) idxAll[side * KTOT + col] = si[0];
}

__global__ void zero_padU(float* __restrict__ U) {
    int idx = blockIdx.x * 256 + threadIdx.x;
    if (idx >= NN * (KP - KTOT)) return;
    int n = idx / (KP - KTOT);
    int c = KTOT + idx % (KP - KTOT);
    U[(size_t)n * KP + c] = 0.0f;
}

// C_l[p][q]: level 0 -> img gather; levels >=1 -> threshold(f - u),
// u = dot(Usm[off+p, 0:off], PhiR[ir[q], 0:off])  -- float4 over k.
__global__ void build_C_kernel(const float* __restrict__ img, const int* __restrict__ idxAll,
                               const float* __restrict__ Usm, const float* __restrict__ PhiR,
                               float* __restrict__ C, int T, int off, int coff) {
    int q = blockIdx.x * 16 + threadIdx.x;
    int p = blockIdx.y * 16 + threadIdx.y;
    if (p >= T || q >= T) return;
    int ip = idxAll[off + p];
    int iq = idxAll[KTOT + off + q];
    float f = img[(size_t)ip * NN + iq];
    float val;
    if (off == 0) {
        val = f;
    } else {
        const float* Ur = Usm  + (size_t)(off + p) * KP;
        const float* Pr = PhiR + (size_t)iq * KP;
        float u0 = 0.f, u1 = 0.f, u2 = 0.f, u3 = 0.f;
        int k = 0, k4 = off & ~3;
        for (; k < k4; k += 4) {
            float4 a = *(const float4*)(Ur + k);
            float4 b = *(const float4*)(Pr + k);
            u0 += a.x * b.x; u1 += a.y * b.y; u2 += a.z * b.z; u3 += a.w * b.w;
        }
        float u = (u0 + u1) + (u2 + u3);
        for (; k < off; ++k) u += Ur[k] * Pr[k];
        float d = f - u;
        val = (fabsf(d) > 0.01f) ? d : 0.0f;
    }
    C[coff + p * T + q] = val;
}

// Usm[r, off+t] = sum_q PhiC[idxAll[r], off+q] * C_l[q][t]   (501 gathered rows)
// grid (ceil(T/64), 126), block (64,4)
__global__ void update_small_kernel(const float* __restrict__ PhiC, const int* __restrict__ idxAll,
                                    const float* __restrict__ C, float* __restrict__ Usm,
                                    int T, int off, int coff) {
    int t = blockIdx.x * 64 + threadIdx.x;
    int r = blockIdx.y * 4 + threadIdx.y;
    if (t >= T || r >= KTOT) return;
    const float* P0 = PhiC + (size_t)idxAll[r] * KP + off;
    const float* Cl = C + coff;
    float a0 = 0.f, a1 = 0.f, a2 = 0.f, a3 = 0.f;
    int q = 0, q4 = T & ~3;
    for (; q < q4; q += 4) {
        a0 += P0[q]     * Cl[(q)     * T + t];
        a1 += P0[q + 1] * Cl[(q + 1) * T + t];
        a2 += P0[q + 2] * Cl[(q + 2) * T + t];
        a3 += P0[q + 3] * Cl[(q + 3) * T + t];
    }
    float acc = (a0 + a1) + (a2 + a3);
    for (; q < T; ++q) acc += P0[q] * Cl[q * T + t];
    Usm[(size_t)r * KP + off + t] = acc;
}

// Full U = per-level PhiC_l x C_l, all 12 (level, t-tile) pairs in parallel.
// grid (12, 256), block (64,4); each thread: 4 rows x 1 col.
__global__ void compute_U_kernel(const float* __restrict__ PhiC, const float* __restrict__ C,
                                 float* __restrict__ U) {
    const int tlvl[12] = {0, 1, 2, 2, 3, 3, 3, 4, 4, 4, 4, 4};
    const int tt0[12]  = {0, 0, 0, 64, 0, 64, 128, 0, 64, 128, 192, 256};
    const int Ts[5]    = {17, 33, 65, 129, 257};
    const int offs[5]  = {0, 17, 50, 115, 244};
    const int coffs[5] = {0, 289, 1378, 5603, 22244};

    const int lvl = tlvl[blockIdx.x];
    const int T   = Ts[lvl];
    const int off = offs[lvl];
    const int t   = tt0[blockIdx.x] + threadIdx.x;
    if (t >= T) return;
    const int n0 = (blockIdx.y * 4 + threadIdx.y) * 4;

    const float* Cl = C + coffs[lvl];
    const float* P0 = PhiC + (size_t)n0 * KP + off;
    float a0 = 0.f, a1 = 0.f, a2 = 0.f, a3 = 0.f;
    int q = 0, q4 = T & ~3;
    for (; q < q4; q += 4) {
        float c0 = Cl[(q)     * T + t];
        float c1 = Cl[(q + 1) * T + t];
        float c2 = Cl[(q + 2) * T + t];
        float c3 = Cl[(q + 3) * T + t];
        a0 += P0[q] * c0 + P0[q + 1] * c1 + P0[q + 2] * c2 + P0[q + 3] * c3;
        a1 += P0[KP + q] * c0 + P0[KP + q + 1] * c1 + P0[KP + q + 2] * c2 + P0[KP + q + 3] * c3;
        a2 += P0[2 * KP + q] * c0 + P0[2 * KP + q + 1] * c1 + P0[2 * KP + q + 2] * c2 + P0[2 * KP + q + 3] * c3;
        a3 += P0[3 * KP + q] * c0 + P0[3 * KP + q + 1] * c1 + P0[3 * KP + q + 2] * c2 + P0[3 * KP + q + 3] * c3;
    }
    for (; q < T; ++q) {
        float c = Cl[q * T + t];
        a0 += P0[q] * c; a1 += P0[KP + q] * c; a2 += P0[2 * KP + q] * c; a3 += P0[3 * KP + q] * c;
    }
    U[(size_t)(n0)     * KP + off + t] = a0;
    U[(size_t)(n0 + 1) * KP + off + t] = a1;
    U[(size_t)(n0 + 2) * KP + off + t] = a2;
    U[(size_t)(n0 + 3) * KP + off + t] = a3;
}

// fp32 -> bf16 hi + bf16 lo(residual). 4 elements/thread.
__global__ void split_kernel(const float* __restrict__ src, __hip_bfloat16* __restrict__ hi,
                             __hip_bfloat16* __restrict__ lo) {
    int i = (blockIdx.x * 256 + threadIdx.x) * 4;
    float4 v = *(const float4*)(src + i);
    __hip_bfloat16 h[4], l[4];
    float vv[4] = {v.x, v.y, v.z, v.w};
    #pragma unroll
    for (int j = 0; j < 4; ++j) {
        h[j] = __float2bfloat16(vv[j]);
        l[j] = __float2bfloat16(vv[j] - __bfloat162float(h[j]));
    }
    *(ushort4*)(hi + i) = *(const ushort4*)h;
    *(ushort4*)(lo + i) = *(const ushort4*)l;
}

// out(4096x4096) = (Ahi+Alo)(4096x512) * (Bhi+Blo)^T, dropping lo*lo.
__global__ __launch_bounds__(256) void gemm_mfma(const short* __restrict__ Ahi,
                                                 const short* __restrict__ Alo,
                                                 const short* __restrict__ Bhi,
                                                 const short* __restrict__ Blo,
                                                 float* __restrict__ out) {
    __shared__ short As_h[128][32];
    __shared__ short As_l[128][32];
    __shared__ short Bs_h[128][32];
    __shared__ short Bs_l[128][32];

    const int tid  = threadIdx.x;
    const int lane = tid & 63;
    const int wave = tid >> 6;
    const int wr   = wave >> 1;
    const int wc   = wave & 1;
    const int row0 = blockIdx.y * 128;
    const int col0 = blockIdx.x * 128;

    f32x4 acc[4][4];
    #pragma unroll
    for (int i = 0; i < 4; ++i)
        #pragma unroll
        for (int j = 0; j < 4; ++j)
            acc[i][j] = (f32x4){0.f, 0.f, 0.f, 0.f};

    const int srow = lane >> 2;
    const int scol = (lane & 3) * 8;

    for (int kc = 0; kc < 16; ++kc) {
        const int k0 = kc * 32;
        #pragma unroll
        for (int s = 0; s < 2; ++s) {
            const int rseg = wave * 32 + s * 16;
            const int r    = rseg + srow;
            const size_t ga = (size_t)(row0 + r) * KP + k0 + scol;
            const size_t gb = (size_t)(col0 + r) * KP + k0 + scol;
            __builtin_amdgcn_global_load_lds(GLB(Ahi + ga), LDS(&As_h[rseg][0]), 16, 0, 0);
            __builtin_amdgcn_global_load_lds(GLB(Alo + ga), LDS(&As_l[rseg][0]), 16, 0, 0);
            __builtin_amdgcn_global_load_lds(GLB(Bhi + gb), LDS(&Bs_h[rseg][0]), 16, 0, 0);
            __builtin_amdgcn_global_load_lds(GLB(Blo + gb), LDS(&Bs_l[rseg][0]), 16, 0, 0);
        }
        __syncthreads();

        const int kb = (lane >> 4) * 8;
        short8 ah[4], al[4], bh[4], bl[4];
        #pragma unroll
        for (int mb = 0; mb < 4; ++mb) {
            const int rr = wr * 64 + mb * 16 + (lane & 15);
            ah[mb] = *(const short8*)&As_h[rr][kb];
            al[mb] = *(const short8*)&As_l[rr][kb];
        }
        #pragma unroll
        for (int nb = 0; nb < 4; ++nb) {
            const int cc = wc * 64 + nb * 16 + (lane & 15);
            bh[nb] = *(const short8*)&Bs_h[cc][kb];
            bl[nb] = *(const short8*)&Bs_l[cc][kb];
        }
        #pragma unroll
        for (int mb = 0; mb < 4; ++mb)
            #pragma unroll
            for (int nb = 0; nb < 4; ++nb) {
                acc[mb][nb] = __builtin_amdgcn_mfma_f32_16x16x32_bf16(ah[mb], bh[nb], acc[mb][nb], 0, 0, 0);
                acc[mb][nb] = __builtin_amdgcn_mfma_f32_16x16x32_bf16(ah[mb], bl[nb], acc[mb][nb], 0, 0, 0);
                acc[mb][nb] = __builtin_amdgcn_mfma_f32_16x16x32_bf16(al[mb], bh[nb], acc[mb][nb], 0, 0, 0);
            }
        __syncthreads();
    }

    const int orow = (lane >> 4) * 4;
    const int ocol = lane & 15;
    #pragma unroll
    for (int mb = 0; mb < 4; ++mb)
        #pragma unroll
        for (int nb = 0; nb < 4; ++nb) {
            const int col = col0 + wc * 64 + nb * 16 + ocol;
            #pragma unroll
            for (int reg = 0; reg < 4; ++reg) {
                const int row = row0 + wr * 64 + mb * 16 + orow + reg;
                out[(size_t)row * NN + col] = acc[mb][nb][reg];
            }
        }
}

extern "C" void kernel_launch(void* const* d_in, const int* in_sizes, int n_in,
                              void* d_out, int out_size, void* d_ws, size_t ws_size,
                              hipStream_t stream) {
    const float* img = (const float*)d_in[0];
    const float* xc  = (const float*)d_in[1];
    const float* xr  = (const float*)d_in[2];
    float* out = (float*)d_out;

    // ws layout (floats): PhiC(8MB) | PhiR(8MB) | U(8MB) | C(353KB) | idx
    // Usm (501x512) overlays the front of U (full U not live during the chain).
    float* PhiC = (float*)d_ws;
    float* PhiR = PhiC + (size_t)NN * KP;
    float* U    = PhiR + (size_t)NN * KP;
    float* C    = U    + (size_t)NN * KP;
    int*   idxAll = (int*)(C + 88293);
    float* Usm  = U;
    // bf16 overlays: Ahi/Alo over PhiC (dead after compute_U), Bhi/Blo over U (dead after split #1)
    short* Ahi = (short*)PhiC;
    short* Alo = Ahi + (size_t)NN * KP;
    short* Bhi = (short*)U;
    short* Blo = Bhi + (size_t)NN * KP;

    phi_kernel<<<dim3(2, NN), 256, 0, stream>>>(xc, xr, PhiC, PhiR);
    nearest_kernel<<<dim3(KTOT, 2), 256, 0, stream>>>(xc, xr, idxAll);

    const int Ts[5]    = {17, 33, 65, 129, 257};
    const int offs[5]  = {0, 17, 50, 115, 244};
    const int coffs[5] = {0, 289, 1378, 5603, 22244};
    for (int l = 0; l < 5; l++) {
        dim3 bgrid((Ts[l] + 15) / 16, (Ts[l] + 15) / 16);
        build_C_kernel<<<bgrid, dim3(16, 16), 0, stream>>>(img, idxAll, Usm, PhiR, C,
                                                           Ts[l], offs[l], coffs[l]);
        if (l < 4) {   // level 4's Usm update is never read
            dim3 ugrid((Ts[l] + 63) / 64, (KTOT + 3) / 4);
            update_small_kernel<<<ugrid, dim3(64, 4), 0, stream>>>(PhiC, idxAll, C, Usm,
                                                                   Ts[l], offs[l], coffs[l]);
        }
    }

    compute_U_kernel<<<dim3(12, NN / 16), dim3(64, 4), 0, stream>>>(PhiC, C, U);
    zero_padU<<<dim3((NN * (KP - KTOT) + 255) / 256), 256, 0, stream>>>(U);

    split_kernel<<<dim3(NN * KP / 1024), 256, 0, stream>>>(U, (__hip_bfloat16*)Ahi,
                                                           (__hip_bfloat16*)Alo);
    split_kernel<<<dim3(NN * KP / 1024), 256, 0, stream>>>(PhiR, (__hip_bfloat16*)Bhi,
                                                           (__hip_bfloat16*)Blo);

    gemm_mfma<<<dim3(NN / 128, NN / 128), 256, 0, stream>>>(Ahi, Alo, Bhi, Blo, out);
}

// Round 4
// 262.642 us; speedup vs baseline: 2.4089x; 1.2959x over previous
//
#include <hip/hip_runtime.h>
#include <hip/hip_bf16.h>
#include <cstddef>
#include <cstdint>

#define NN 4096
#define KP 512          // padded K (501 real cols)
#define KTOT 501

typedef __attribute__((ext_vector_type(8))) short short8;
typedef __attribute__((ext_vector_type(4))) float f32x4;

#define GLB(p) ((const __attribute__((address_space(1))) void*)(p))
#define LDS(p) ((__attribute__((address_space(3))) void*)(p))

// phi(x) = sin(pi x)/(pi x) * exp(-x^2/(2*3.2^2)), phi(0)=1.
__device__ __forceinline__ float phi_eval(float x) {
    if (x == 0.0f) return 1.0f;
    const float PI_F = 3.14159265358979323846f;
    float rn = rintf(x);
    float r  = x - rn;
    float s  = __sinf(PI_F * r);
    if (((int)rn) & 1) s = -s;
    float e  = __expf(-x * x * (1.0f / 20.48f));
    return __fdividef(s * e, PI_F * x);
}

__device__ __forceinline__ void col_to_level(int col, int& l, int& off) {
    if      (col < 17)  { l = 0; off = 0;   }
    else if (col < 50)  { l = 1; off = 17;  }
    else if (col < 115) { l = 2; off = 50;  }
    else if (col < 244) { l = 3; off = 115; }
    else                { l = 4; off = 244; }
}

// dot of two contiguous fp32 vectors sharing alignment mod 16B.
__device__ __forceinline__ float dot_vec(const float* __restrict__ a,
                                         const float* __restrict__ b, int n) {
    float s = 0.f;
    int k = 0;
    int head = (int)((4 - (((uintptr_t)a >> 2) & 3)) & 3);
    if (head > n) head = n;
    for (; k < head; ++k) s += a[k] * b[k];
    float s0 = 0.f, s1 = 0.f, s2 = 0.f, s3 = 0.f;
    for (; k + 4 <= n; k += 4) {
        float4 x = *(const float4*)(a + k);
        float4 y = *(const float4*)(b + k);
        s0 += x.x * y.x; s1 += x.y * y.y; s2 += x.z * y.z; s3 += x.w * y.w;
    }
    s += (s0 + s1) + (s2 + s3);
    for (; k < n; ++k) s += a[k] * b[k];
    return s;
}

__global__ void phi_kernel(const float* __restrict__ xc, const float* __restrict__ xr,
                           float* __restrict__ PhiC, float* __restrict__ PhiR) {
    int col = blockIdx.x * blockDim.x + threadIdx.x;   // 0..511
    int n   = blockIdx.y;
    float pc = 0.0f, pr = 0.0f;
    if (col < KTOT) {
        int l, off; col_to_level(col, l, off);
        int s = 8 << l;
        float fo = (float)(col - off - s);
        float fs = (float)s;
        pc = phi_eval(fs * xc[n] - fo);
        pr = phi_eval(fs * xr[n] - fo);
    }
    PhiC[(size_t)n * KP + col] = pc;
    PhiR[(size_t)n * KP + col] = pr;
}

__global__ void nearest_kernel(const float* __restrict__ xc, const float* __restrict__ xr,
                               int* __restrict__ idxAll) {
    int col  = blockIdx.x;
    int side = blockIdx.y;
    const float* x = side ? xr : xc;
    int l, off; col_to_level(col, l, off);
    int s = 8 << l;
    float target = (float)(col - off - s) / (float)s;

    __shared__ float sv[256];
    __shared__ int   si[256];
    int tid = threadIdx.x;
    float best = 1e30f; int bidx = 0;
    for (int n = tid; n < NN; n += 256) {
        float d = fabsf(x[n] - target);
        if (d < best) { best = d; bidx = n; }
    }
    sv[tid] = best; si[tid] = bidx;
    __syncthreads();
    for (int w = 128; w > 0; w >>= 1) {
        if (tid < w) {
            float ov = sv[tid + w]; int oi = si[tid + w];
            if (ov < sv[tid] || (ov == sv[tid] && oi < si[tid])) { sv[tid] = ov; si[tid] = oi; }
        }
        __syncthreads();
    }
    if (tid == 0) idxAll[side * KTOT + col] = si[0];
}

// zero dense CdT (512x512 fp32)
__global__ void zero_CdT(float* __restrict__ CdT) {
    int i = (blockIdx.x * 256 + threadIdx.x) * 4;
    *(float4*)(CdT + i) = make_float4(0.f, 0.f, 0.f, 0.f);
}

// C_l[p][q] (p=c-side, q=r-side): level 0 -> img gather; else threshold(f - u).
// Writes dense transposed: CdT[(off+q), (off+p)] = C_l[p][q].
__global__ void build_C_kernel(const float* __restrict__ img, const int* __restrict__ idxAll,
                               const float* __restrict__ Usm, const float* __restrict__ PhiR,
                               float* __restrict__ CdT, int T, int off) {
    int q = blockIdx.x * 16 + threadIdx.x;
    int p = blockIdx.y * 16 + threadIdx.y;
    if (p >= T || q >= T) return;
    int ip = idxAll[off + p];
    int iq = idxAll[KTOT + off + q];
    float f = img[(size_t)ip * NN + iq];
    float val;
    if (off == 0) {
        val = f;
    } else {
        const float* Ur = Usm  + (size_t)(off + p) * KP;
        const float* Pr = PhiR + (size_t)iq * KP;
        float u = dot_vec(Ur, Pr, off);
        float d = f - u;
        val = (fabsf(d) > 0.01f) ? d : 0.0f;
    }
    CdT[(size_t)(off + q) * KP + (off + p)] = val;
}

// Usm[r, off+t] = dot(PhiC[idxAll[r], off:off+T], CdT[off+t, off:off+T])
// grid (ceil(T/64), 126), block (64,4)
__global__ void update_small_kernel(const float* __restrict__ PhiC, const int* __restrict__ idxAll,
                                    const float* __restrict__ CdT, float* __restrict__ Usm,
                                    int T, int off) {
    int t = blockIdx.x * 64 + threadIdx.x;
    int r = blockIdx.y * 4 + threadIdx.y;
    if (t >= T || r >= KTOT) return;
    const float* P0 = PhiC + (size_t)idxAll[r] * KP + off;
    const float* Cr = CdT  + (size_t)(off + t) * KP + off;
    Usm[(size_t)r * KP + off + t] = dot_vec(P0, Cr, T);
}

// fp32 -> bf16 hi + bf16 lo(residual). 4 elements/thread.
__global__ void split_kernel(const float* __restrict__ src, __hip_bfloat16* __restrict__ hi,
                             __hip_bfloat16* __restrict__ lo) {
    int i = (blockIdx.x * 256 + threadIdx.x) * 4;
    float4 v = *(const float4*)(src + i);
    __hip_bfloat16 h[4], l[4];
    float vv[4] = {v.x, v.y, v.z, v.w};
    #pragma unroll
    for (int j = 0; j < 4; ++j) {
        h[j] = __float2bfloat16(vv[j]);
        l[j] = __float2bfloat16(vv[j] - __bfloat162float(h[j]));
    }
    *(ushort4*)(hi + i) = *(const ushort4*)h;
    *(ushort4*)(lo + i) = *(const ushort4*)l;
}

// Shared MFMA tile body: 128x128 tile, 256 threads, split-bf16 3-term product.
// acc layout per m89: col = lane&15, row = (lane>>4)*4 + reg.
#define GEMM_BODY(Ahi_, Alo_, Bhi_, Blo_)                                              \
    __shared__ short As_h[128][32];                                                    \
    __shared__ short As_l[128][32];                                                    \
    __shared__ short Bs_h[128][32];                                                    \
    __shared__ short Bs_l[128][32];                                                    \
    const int tid  = threadIdx.x;                                                      \
    const int lane = tid & 63;                                                         \
    const int wave = tid >> 6;                                                         \
    const int wr   = wave >> 1;                                                        \
    const int wc   = wave & 1;                                                         \
    const int row0 = blockIdx.y * 128;                                                 \
    const int col0 = blockIdx.x * 128;                                                 \
    f32x4 acc[4][4];                                                                   \
    _Pragma("unroll")                                                                  \
    for (int i = 0; i < 4; ++i)                                                        \
        _Pragma("unroll")                                                              \
        for (int j = 0; j < 4; ++j) acc[i][j] = (f32x4){0.f, 0.f, 0.f, 0.f};           \
    const int srow = lane >> 2;                                                        \
    const int scol = (lane & 3) * 8;                                                   \
    for (int kc = 0; kc < 16; ++kc) {                                                  \
        const int k0 = kc * 32;                                                        \
        _Pragma("unroll")                                                              \
        for (int s = 0; s < 2; ++s) {                                                  \
            const int rseg = wave * 32 + s * 16;                                       \
            const int r    = rseg + srow;                                              \
            const size_t ga = (size_t)(row0 + r) * KP + k0 + scol;                     \
            const size_t gb = (size_t)(col0 + r) * KP + k0 + scol;                     \
            __builtin_amdgcn_global_load_lds(GLB(Ahi_ + ga), LDS(&As_h[rseg][0]), 16, 0, 0); \
            __builtin_amdgcn_global_load_lds(GLB(Alo_ + ga), LDS(&As_l[rseg][0]), 16, 0, 0); \
            __builtin_amdgcn_global_load_lds(GLB(Bhi_ + gb), LDS(&Bs_h[rseg][0]), 16, 0, 0); \
            __builtin_amdgcn_global_load_lds(GLB(Blo_ + gb), LDS(&Bs_l[rseg][0]), 16, 0, 0); \
        }                                                                              \
        __syncthreads();                                                               \
        const int kb = (lane >> 4) * 8;                                                \
        short8 ah[4], al[4], bh[4], bl[4];                                             \
        _Pragma("unroll")                                                              \
        for (int mb = 0; mb < 4; ++mb) {                                               \
            const int rr = wr * 64 + mb * 16 + (lane & 15);                            \
            ah[mb] = *(const short8*)&As_h[rr][kb];                                    \
            al[mb] = *(const short8*)&As_l[rr][kb];                                    \
        }                                                                              \
        _Pragma("unroll")                                                              \
        for (int nb = 0; nb < 4; ++nb) {                                               \
            const int cc = wc * 64 + nb * 16 + (lane & 15);                            \
            bh[nb] = *(const short8*)&Bs_h[cc][kb];                                    \
            bl[nb] = *(const short8*)&Bs_l[cc][kb];                                    \
        }                                                                              \
        _Pragma("unroll")                                                              \
        for (int mb = 0; mb < 4; ++mb)                                                 \
            _Pragma("unroll")                                                          \
            for (int nb = 0; nb < 4; ++nb) {                                           \
                acc[mb][nb] = __builtin_amdgcn_mfma_f32_16x16x32_bf16(ah[mb], bh[nb], acc[mb][nb], 0, 0, 0); \
                acc[mb][nb] = __builtin_amdgcn_mfma_f32_16x16x32_bf16(ah[mb], bl[nb], acc[mb][nb], 0, 0, 0); \
                acc[mb][nb] = __builtin_amdgcn_mfma_f32_16x16x32_bf16(al[mb], bh[nb], acc[mb][nb], 0, 0, 0); \
            }                                                                          \
        __syncthreads();                                                               \
    }                                                                                  \
    const int orow = (lane >> 4) * 4;                                                  \
    const int ocol = lane & 15;

// gemm2: fp32 output, ld = NN
__global__ __launch_bounds__(256) void gemm_mfma_f32out(const short* __restrict__ Ahi,
                                                        const short* __restrict__ Alo,
                                                        const short* __restrict__ Bhi,
                                                        const short* __restrict__ Blo,
                                                        float* __restrict__ out) {
    GEMM_BODY(Ahi, Alo, Bhi, Blo)
    #pragma unroll
    for (int mb = 0; mb < 4; ++mb)
        #pragma unroll
        for (int nb = 0; nb < 4; ++nb) {
            const int col = col0 + wc * 64 + nb * 16 + ocol;
            #pragma unroll
            for (int reg = 0; reg < 4; ++reg) {
                const int row = row0 + wr * 64 + mb * 16 + orow + reg;
                out[(size_t)row * NN + col] = acc[mb][nb][reg];
            }
        }
}

// gemm1: split-bf16 output (hi + residual-lo), ld = KP
__global__ __launch_bounds__(256) void gemm_mfma_splitout(const short* __restrict__ Ahi,
                                                          const short* __restrict__ Alo,
                                                          const short* __restrict__ Bhi,
                                                          const short* __restrict__ Blo,
                                                          unsigned short* __restrict__ Oh,
                                                          unsigned short* __restrict__ Ol) {
    GEMM_BODY(Ahi, Alo, Bhi, Blo)
    #pragma unroll
    for (int mb = 0; mb < 4; ++mb)
        #pragma unroll
        for (int nb = 0; nb < 4; ++nb) {
            const int col = col0 + wc * 64 + nb * 16 + ocol;
            #pragma unroll
            for (int reg = 0; reg < 4; ++reg) {
                const int row = row0 + wr * 64 + mb * 16 + orow + reg;
                float v = acc[mb][nb][reg];
                __hip_bfloat16 hb = __float2bfloat16(v);
                __hip_bfloat16 lb = __float2bfloat16(v - __bfloat162float(hb));
                Oh[(size_t)row * KP + col] = *(unsigned short*)&hb;
                Ol[(size_t)row * KP + col] = *(unsigned short*)&lb;
            }
        }
}

extern "C" void kernel_launch(void* const* d_in, const int* in_sizes, int n_in,
                              void* d_out, int out_size, void* d_ws, size_t ws_size,
                              hipStream_t stream) {
    const float* img = (const float*)d_in[0];
    const float* xc  = (const float*)d_in[1];
    const float* xr  = (const float*)d_in[2];
    float* out = (float*)d_out;

    const size_t M2 = (size_t)NN * KP;           // 2M elements
    // ws layout (floats): PhiC(2M) | PhiR(2M) | Ubuf(2M) | CdT(256K) | CdTsplit(256K) | idx
    float* PhiC = (float*)d_ws;
    float* PhiR = PhiC + M2;
    float* Ubuf = PhiR + M2;
    float* CdT  = Ubuf + M2;
    float* CdTs = CdT + (size_t)KP * KP;
    int*   idxAll = (int*)(CdTs + (size_t)KP * KP);
    float* Usm  = Ubuf;                           // 501x512 during chain
    // post-chain overlays:
    short* PRh = (short*)Ubuf;                    // split(PhiR) -> Ubuf region
    short* PRl = PRh + M2;
    short* PCh = (short*)PhiR;                    // split(PhiC) -> PhiR region
    short* PCl = PCh + M2;
    short* Ch  = (short*)CdTs;                    // split(CdT)
    short* Cl  = Ch + (size_t)KP * KP;
    unsigned short* Uh = (unsigned short*)PhiC;   // gemm1 out -> PhiC region
    unsigned short* Ul = Uh + M2;

    phi_kernel<<<dim3(2, NN), 256, 0, stream>>>(xc, xr, PhiC, PhiR);
    nearest_kernel<<<dim3(KTOT, 2), 256, 0, stream>>>(xc, xr, idxAll);
    zero_CdT<<<dim3(KP * KP / 1024), 256, 0, stream>>>(CdT);

    const int Ts[5]   = {17, 33, 65, 129, 257};
    const int offs[5] = {0, 17, 50, 115, 244};
    for (int l = 0; l < 5; l++) {
        dim3 bgrid((Ts[l] + 15) / 16, (Ts[l] + 15) / 16);
        build_C_kernel<<<bgrid, dim3(16, 16), 0, stream>>>(img, idxAll, Usm, PhiR, CdT,
                                                           Ts[l], offs[l]);
        if (l < 4) {
            dim3 ugrid((Ts[l] + 63) / 64, (KTOT + 3) / 4);
            update_small_kernel<<<ugrid, dim3(64, 4), 0, stream>>>(PhiC, idxAll, CdT, Usm,
                                                                   Ts[l], offs[l]);
        }
    }

    // splits (ordering matters for overlays: PhiR->Ubuf first, then PhiC->PhiR region)
    split_kernel<<<dim3((int)(M2 / 1024)), 256, 0, stream>>>(PhiR, (__hip_bfloat16*)PRh,
                                                             (__hip_bfloat16*)PRl);
    split_kernel<<<dim3((int)(M2 / 1024)), 256, 0, stream>>>(PhiC, (__hip_bfloat16*)PCh,
                                                             (__hip_bfloat16*)PCl);
    split_kernel<<<dim3(KP * KP / 1024), 256, 0, stream>>>(CdT, (__hip_bfloat16*)Ch,
                                                           (__hip_bfloat16*)Cl);

    // gemm1: U(4096x512) = PhiC x CdT^T, split-bf16 out (overwrites PhiC region)
    gemm_mfma_splitout<<<dim3(KP / 128, NN / 128), 256, 0, stream>>>(PCh, PCl, Ch, Cl, Uh, Ul);

    // gemm2: out(4096x4096) = U x PhiR^T
    gemm_mfma_f32out<<<dim3(NN / 128, NN / 128), 256, 0, stream>>>((const short*)Uh, (const short*)Ul,
                                                                   PRh, PRl, out);
}